// Round 6
// baseline (157.401 us; speedup 1.0000x reference)
//
#include <hip/hip_runtime.h>
#include <hip/hip_bf16.h>
#include <math.h>

#define CDIM 64
#define BATCH 2
#define KSPLIT 8
#define TK 64
#define M_FIX 44.0f        // fixed softmax max, log2 units (log2e folded into K)
#define LOG2E 1.44269504f

typedef __bf16 bf16x8 __attribute__((ext_vector_type(8)));
typedef __bf16 bf16x4 __attribute__((ext_vector_type(4)));
typedef float f32x4 __attribute__((ext_vector_type(4)));
typedef float f32x16 __attribute__((ext_vector_type(16)));

// ---------------------------------------------------------------------------
// Stage 1: fused 1x1-conv projections via MFMA, hi/lo bf16 split.
//   Q[n][c] (bf16), K[n][c] (bf16, scaled by log2e), V[c][n] (bf16, BN folded)
// grid (N/64, 3, B), block 256 (4 waves x 16 n).  [unchanged from R5]
// ---------------------------------------------------------------------------
__global__ __launch_bounds__(256) void gfa_stage1(
    const float* __restrict__ feature,
    const float* __restrict__ wa, const float* __restrict__ ba,
    const float* __restrict__ wb, const float* __restrict__ bb,
    const float* __restrict__ wm, const float* __restrict__ bm,
    const float* __restrict__ gma, const float* __restrict__ bta,
    const float* __restrict__ mean, const float* __restrict__ var,
    __bf16* __restrict__ Q, __bf16* __restrict__ K, __bf16* __restrict__ V,
    int N)
{
    const int tid  = threadIdx.x;
    const int w    = tid >> 6;
    const int lane = tid & 63;
    const int l15  = lane & 15;
    const int quad = lane >> 4;
    const int n0    = blockIdx.x * 64;
    const int which = blockIdx.y;
    const int b     = blockIdx.z;

    __shared__ __align__(16) char s1lds[35328];
    float*  Xs  = (float*)s1lds;              // [64][66] fp32
    __bf16* Whi = (__bf16*)(s1lds + 16896);   // [64][72]
    __bf16* Wlo = (__bf16*)(s1lds + 26112);   // [64][72]
    __bf16* Ts  = (__bf16*)s1lds;             // epilogue transpose (aliases Xs)

    const float* wsel = (which == 0) ? wa : (which == 1) ? wb : wm;
    const float* bsel = (which == 0) ? ba : (which == 1) ? bb : bm;
    const float wscale = (which == 1) ? LOG2E : 1.0f;   // fold log2e into K

    const float* fb = feature + (size_t)b * CDIM * N;
#pragma unroll
    for (int p = 0; p < 4; p++) {
        int idx = p * 256 + tid;
        int c = idx >> 4, n4 = (idx & 15) << 2;
        float4 v = *(const float4*)&fb[(size_t)c * N + n0 + n4];
        *(float2*)&Xs[c * 66 + n4]     = make_float2(v.x, v.y);
        *(float2*)&Xs[c * 66 + n4 + 2] = make_float2(v.z, v.w);
    }
#pragma unroll
    for (int p = 0; p < 4; p++) {
        int idx = p * 256 + tid;
        int o = idx >> 4, c4 = (idx & 15) << 2;
        float4 v = *(const float4*)&wsel[o * 64 + c4];
        bf16x4 hi, lo;
        float vv[4] = {v.x * wscale, v.y * wscale, v.z * wscale, v.w * wscale};
#pragma unroll
        for (int r = 0; r < 4; r++) {
            hi[r] = (__bf16)vv[r];
            lo[r] = (__bf16)(vv[r] - (float)hi[r]);
        }
        *(bf16x4*)&Whi[o * 72 + c4] = hi;
        *(bf16x4*)&Wlo[o * 72 + c4] = lo;
    }
    __syncthreads();

    const int nb = w * 16;
    bf16x8 xh[2], xl[2];
#pragma unroll
    for (int kc = 0; kc < 2; kc++) {
#pragma unroll
        for (int j = 0; j < 8; j++) {
            float xv = Xs[(kc * 32 + quad * 8 + j) * 66 + nb + l15];
            __bf16 h = (__bf16)xv;
            xh[kc][j] = h;
            xl[kc][j] = (__bf16)(xv - (float)h);
        }
    }

    f32x4 acc[4];
#pragma unroll
    for (int ot = 0; ot < 4; ot++) acc[ot] = (f32x4){0.f, 0.f, 0.f, 0.f};

#pragma unroll
    for (int ot = 0; ot < 4; ot++) {
#pragma unroll
        for (int kc = 0; kc < 2; kc++) {
            bf16x8 wh = *(const bf16x8*)&Whi[(ot * 16 + l15) * 72 + kc * 32 + quad * 8];
            bf16x8 wl = *(const bf16x8*)&Wlo[(ot * 16 + l15) * 72 + kc * 32 + quad * 8];
            acc[ot] = __builtin_amdgcn_mfma_f32_16x16x32_bf16(wh, xh[kc], acc[ot], 0, 0, 0);
            acc[ot] = __builtin_amdgcn_mfma_f32_16x16x32_bf16(wl, xh[kc], acc[ot], 0, 0, 0);
            acc[ot] = __builtin_amdgcn_mfma_f32_16x16x32_bf16(wh, xl[kc], acc[ot], 0, 0, 0);
        }
    }

    __syncthreads();
    if (which < 2) {
        __bf16* O = (which == 0 ? Q : K) + (size_t)b * N * CDIM;
#pragma unroll
        for (int ot = 0; ot < 4; ot++) {
            int o0 = ot * 16 + quad * 4;
            float4 b4 = *(const float4*)&bsel[o0];
            float bv[4] = {b4.x * wscale, b4.y * wscale, b4.z * wscale, b4.w * wscale};
            bf16x4 pk;
#pragma unroll
            for (int r = 0; r < 4; r++) pk[r] = (__bf16)(acc[ot][r] + bv[r]);
            *(bf16x4*)&Ts[(nb + l15) * 68 + o0] = pk;
        }
        __syncthreads();
#pragma unroll
        for (int p = 0; p < 2; p++) {
            int idx = p * 256 + tid;
            int row = idx >> 3, c8 = (idx & 7) * 8;
            *(int4*)&O[(size_t)(n0 + row) * CDIM + c8] = *(int4*)&Ts[row * 68 + c8];
        }
    } else {
        __bf16* Vb = V + (size_t)b * CDIM * N;
#pragma unroll
        for (int ot = 0; ot < 4; ot++) {
            int o0 = ot * 16 + quad * 4;
            float4 b4 = *(const float4*)&bsel[o0];
            float4 m4 = *(const float4*)&mean[o0];
            float4 v4 = *(const float4*)&var[o0];
            float4 g4 = *(const float4*)&gma[o0];
            float4 t4 = *(const float4*)&bta[o0];
            float bv[4] = {b4.x, b4.y, b4.z, b4.w};
            float mv[4] = {m4.x, m4.y, m4.z, m4.w};
            float vv[4] = {v4.x, v4.y, v4.z, v4.w};
            float gv[4] = {g4.x, g4.y, g4.z, g4.w};
            float tv[4] = {t4.x, t4.y, t4.z, t4.w};
#pragma unroll
            for (int r = 0; r < 4; r++) {
                float s = gv[r] * rsqrtf(vv[r] + 1e-5f);
                float val = (acc[ot][r] + bv[r] - mv[r]) * s + tv[r];
                Ts[(o0 + r) * 68 + nb + l15] = (__bf16)val;
            }
        }
        __syncthreads();
#pragma unroll
        for (int p = 0; p < 2; p++) {
            int idx = p * 256 + tid;
            int row = idx >> 3, n8 = (idx & 7) * 8;
            *(int4*)&Vb[(size_t)row * N + n0 + n8] = *(int4*)&Ts[row * 68 + n8];
        }
    }
}

// ---------------------------------------------------------------------------
// Stage 2: flash attention, kv-split, fixed-max softmax, 32x32x16 MFMA,
// DOUBLE-BUFFERED K/V staging: ONE barrier per iter; next tile's global
// loads issue right after the barrier and are consumed (reg->ds_write) at
// the top of the next iter, so HBM latency hides behind a full compute iter.
// P handled in 32-kv chunks (QK(kvt) -> softmax -> PV(kvt)) so the per-wave
// P strip is [64 q][72 B] and total LDS stays at 55296 B (2 blocks/CU).
// launch_bounds(256,2): 256-VGPR budget -> prefetch regs don't spill.
// grid (N/256, KSPLIT, B) = 512 blocks (all resident).
// ---------------------------------------------------------------------------
__global__ __launch_bounds__(256, 2) void gfa_stage2(
    const __bf16* __restrict__ Q, const __bf16* __restrict__ K,
    const __bf16* __restrict__ V,
    __bf16* __restrict__ Upart, float* __restrict__ stats, int N)
{
    const int tid  = threadIdx.x;
    const int w    = tid >> 6;
    const int lane = tid & 63;
    const int l31  = lane & 31;
    const int half = lane >> 5;
    const int qt_  = blockIdx.x;
    const int sp   = blockIdx.y;
    const int b    = blockIdx.z;
    const int qb   = qt_ * 256 + w * 64;
    const int QT   = N >> 6;

    __shared__ __align__(16) char lds[55296];
    // [0..18432): buf0 = K[64][144] + V[64][144]; [18432..36864): buf1;
    // [36864..55296): per-wave P strips [64 q][72 B] (32-kv chunks)
    char* Pw = lds + 36864 + w * 4608;

    const __bf16* Qg = Q + (size_t)b * N * CDIM;
    const __bf16* Kg = K + (size_t)b * N * CDIM;
    const __bf16* Vg = V + (size_t)b * CDIM * N;
    const int kvb = sp * (N / KSPLIT);
    const int r8 = tid >> 3, c16 = (tid & 7) * 16;

    // Q B-fragments (loop-invariant)
    bf16x8 qf[2][4];
#pragma unroll
    for (int qt = 0; qt < 2; qt++)
#pragma unroll
        for (int kc = 0; kc < 4; kc++)
            qf[qt][kc] = *(const bf16x8*)((const char*)Qg
                + (size_t)(qb + qt * 32 + l31) * 128 + kc * 32 + half * 16);

    f32x16 acc[2][2];
#pragma unroll
    for (int qt = 0; qt < 2; qt++)
#pragma unroll
        for (int ct = 0; ct < 2; ct++)
#pragma unroll
            for (int r = 0; r < 16; r++) acc[qt][ct][r] = 0.f;
    float l_run[2] = {0.f, 0.f};

    // preload tile 0 into regs
    int4 kr[2], vr[2];
#pragma unroll
    for (int p = 0; p < 2; p++) {
        kr[p] = *(const int4*)((const char*)Kg + (size_t)(kvb + p * 32 + r8) * 128 + c16);
        vr[p] = *(const int4*)((const char*)Vg + ((size_t)(p * 32 + r8) * N + kvb) * 2 + c16);
    }

    const int NIT = N / KSPLIT / TK;
    for (int it = 0; it < NIT; it++) {
        char* Kt = lds + (it & 1) * 18432;
        char* Vt = Kt + 9216;
        // commit staged regs to this iter's buffer
#pragma unroll
        for (int p = 0; p < 2; p++) {
            *(int4*)(Kt + (p * 32 + r8) * 144 + c16) = kr[p];
            *(int4*)(Vt + (p * 32 + r8) * 144 + c16) = vr[p];
        }
        __syncthreads();   // the ONLY barrier per iter

        if (it + 1 < NIT) {   // prefetch next tile; consumed next iter (no reader before then)
            const int kv1 = kvb + (it + 1) * TK;
#pragma unroll
            for (int p = 0; p < 2; p++) {
                kr[p] = *(const int4*)((const char*)Kg + (size_t)(kv1 + p * 32 + r8) * 128 + c16);
                vr[p] = *(const int4*)((const char*)Vg + ((size_t)(p * 32 + r8) * N + kv1) * 2 + c16);
            }
        }

#pragma unroll
        for (int kvt = 0; kvt < 2; kvt++) {
            // QK^T for this 32-kv chunk; kf shared across the 2 q-tiles
            bf16x8 kf[4];
#pragma unroll
            for (int kc = 0; kc < 4; kc++)
                kf[kc] = *(const bf16x8*)(Kt + (kvt * 32 + l31) * 144 + kc * 32 + half * 16);
#pragma unroll
            for (int qt = 0; qt < 2; qt++) {
                f32x16 s16;
#pragma unroll
                for (int r = 0; r < 16; r++) s16[r] = 0.f;
#pragma unroll
                for (int kc = 0; kc < 4; kc++)
                    s16 = __builtin_amdgcn_mfma_f32_32x32x16_bf16(kf[kc], qf[qt][kc], s16, 0, 0, 0);
                float s = 0.f;
#pragma unroll
                for (int rg = 0; rg < 4; rg++) {
                    bf16x4 pb;
#pragma unroll
                    for (int r = 0; r < 4; r++) {
                        float p = __builtin_amdgcn_exp2f(s16[rg * 4 + r] - M_FIX);
                        s += p;
                        pb[r] = (__bf16)p;
                    }
                    // local kv = rg*8 + half*4 (C-layout rows), [q][kv32] strip
                    *(bf16x4*)(Pw + (qt * 32 + l31) * 72 + rg * 16 + half * 8) = pb;
                }
                l_run[qt] += s;
            }
            // PV for this 32-kv chunk (2 k-blocks of 16)
#pragma unroll
            for (int ks = 0; ks < 2; ks++) {
                bf16x8 vfv[2], pfv[2];
#pragma unroll
                for (int ct = 0; ct < 2; ct++)
                    vfv[ct] = *(const bf16x8*)(Vt + (ct * 32 + l31) * 144
                                               + kvt * 64 + ks * 32 + half * 16);
#pragma unroll
                for (int qt = 0; qt < 2; qt++) {
                    const char* pr = Pw + (qt * 32 + l31) * 72 + ks * 32 + half * 16;
                    bf16x4 plo = *(const bf16x4*)(pr);
                    bf16x4 phi = *(const bf16x4*)(pr + 8);
#pragma unroll
                    for (int j = 0; j < 4; j++) { pfv[qt][j] = plo[j]; pfv[qt][j + 4] = phi[j]; }
                }
#pragma unroll
                for (int qt = 0; qt < 2; qt++)
#pragma unroll
                    for (int ct = 0; ct < 2; ct++)
                        acc[qt][ct] = __builtin_amdgcn_mfma_f32_32x32x16_bf16(vfv[ct], pfv[qt], acc[qt][ct], 0, 0, 0);
            }
        }
    }

    // epilogue: per-wave 64-q tile -> Upart (bf16) + stats
    const int qt64 = qt_ * 4 + w;
    __bf16* Ub = Upart + ((size_t)(b * KSPLIT + sp) * QT + qt64) * 4096;
    float*  Sb = stats + ((size_t)(b * KSPLIT + sp) * QT + qt64) * 64;
#pragma unroll
    for (int qt = 0; qt < 2; qt++) {
        float s = l_run[qt] + __shfl_xor(l_run[qt], 32);
        int qq = qt * 32 + l31;
#pragma unroll
        for (int ct = 0; ct < 2; ct++)
#pragma unroll
            for (int r = 0; r < 16; r++) {
                int c = ct * 32 + (r & 3) + 8 * (r >> 2) + 4 * half;
                Ub[c * 64 + qq] = (__bf16)acc[qt][ct][r];
            }
        if (half == 0) Sb[qq] = s;
    }
}

// ---------------------------------------------------------------------------
// Reduce: plain sum across KSPLIT + residual epilogue.  [unchanged from R5]
// grid (N/64, 4, B), block 256: 64 q x 16 c per block; thread = 1 q x 4 c.
// ---------------------------------------------------------------------------
__global__ __launch_bounds__(256) void gfa_reduce(
    const float* __restrict__ feature, const float* __restrict__ alpha_p,
    const __bf16* __restrict__ Upart, const float* __restrict__ stats,
    float* __restrict__ out, int N)
{
    const int qt = blockIdx.x;
    const int cq = blockIdx.y;
    const int b  = blockIdx.z;
    const int q  = threadIdx.x & 63;
    const int c0 = cq * 16 + (threadIdx.x >> 6) * 4;
    const int QT = N >> 6;

    float L = 0.f;
#pragma unroll
    for (int s = 0; s < KSPLIT; s++)
        L += stats[((size_t)(b * KSPLIT + s) * QT + qt) * 64 + q];

    float u[4] = {0.f, 0.f, 0.f, 0.f};
#pragma unroll
    for (int s = 0; s < KSPLIT; s++) {
        const __bf16* Ub = Upart + ((size_t)(b * KSPLIT + s) * QT + qt) * 4096;
#pragma unroll
        for (int i = 0; i < 4; i++)
            u[i] += (float)Ub[(c0 + i) * 64 + q];
    }

    float scale = 2.f * alpha_p[0] / L;
    const int n = qt * 64 + q;
#pragma unroll
    for (int i = 0; i < 4; i++) {
        size_t gi = ((size_t)b * CDIM + c0 + i) * N + n;
        out[gi] = 2.f * feature[gi] + scale * u[i];
    }
}

// ---------------------------------------------------------------------------
extern "C" void kernel_launch(void* const* d_in, const int* in_sizes, int n_in,
                              void* d_out, int out_size, void* d_ws, size_t ws_size,
                              hipStream_t stream) {
    const float* feature = (const float*)d_in[0];
    const float* wa   = (const float*)d_in[1];
    const float* ba   = (const float*)d_in[2];
    const float* wb   = (const float*)d_in[3];
    const float* bb   = (const float*)d_in[4];
    const float* wm   = (const float*)d_in[5];
    const float* bm   = (const float*)d_in[6];
    const float* gma  = (const float*)d_in[7];
    const float* bta  = (const float*)d_in[8];
    const float* mean = (const float*)d_in[9];
    const float* var  = (const float*)d_in[10];
    const float* alpha = (const float*)d_in[11];
    const int N = in_sizes[0] / (BATCH * CDIM);   // 8192

    __bf16* Q = (__bf16*)d_ws;
    __bf16* K = Q + (size_t)BATCH * N * CDIM;
    __bf16* V = K + (size_t)BATCH * N * CDIM;
    __bf16* Upart = V + (size_t)BATCH * N * CDIM;
    float* stats = (float*)(Upart + (size_t)BATCH * KSPLIT * (N / 64) * 4096);

    dim3 g1(N / 64, 3, BATCH);
    gfa_stage1<<<g1, 256, 0, stream>>>(feature, wa, ba, wb, bb, wm, bm,
                                       gma, bta, mean, var, Q, K, V, N);
    dim3 g2(N / 256, KSPLIT, BATCH);
    gfa_stage2<<<g2, 256, 0, stream>>>(Q, K, V, Upart, stats, N);
    dim3 g3(N / 64, 4, BATCH);
    gfa_reduce<<<g3, 256, 0, stream>>>(feature, alpha, Upart, stats, (float*)d_out, N);
}